// Round 7
// baseline (74.518 us; speedup 1.0000x reference)
//
#include <hip/hip_runtime.h>
#include <hip/hip_bf16.h>
#include <cstdint>
#include <cstddef>

#define N_PTS 4096
#define DIM   2048
#define NCLS  64
#define NTK   (DIM / 64)   // 32 K-steps of 64

typedef __bf16 bf16x8 __attribute__((ext_vector_type(8)));
typedef float  f32x4  __attribute__((ext_vector_type(4)));
typedef unsigned short u16x8 __attribute__((ext_vector_type(8)));

__device__ __forceinline__ unsigned short f32_to_bf16_rne(float f) {
  unsigned u = __float_as_uint(f);
  u += 0x7fffu + ((u >> 16) & 1u);
  return (unsigned short)(u >> 16);
}
__device__ __forceinline__ int imin(int a, int b) { return a < b ? a : b; }

__device__ __forceinline__ void load_lds16(const void* g, void* l) {
  __builtin_amdgcn_global_load_lds(
      (const __attribute__((address_space(1))) void*)g,
      (__attribute__((address_space(3))) void*)l, 16, 0, 0);
}

// ---------------- bucket: class histogram + exclusive scan (no scatter) ------------
__global__ __launch_bounds__(1024) void bucket_kernel(const int* __restrict__ tgt,
                                                      int* __restrict__ cbase,
                                                      int* __restrict__ ccnt,
                                                      int* __restrict__ cnt) {
  __shared__ int hist[16][NCLS];
  const int tid = threadIdx.x, w = tid >> 6, l = tid & 63;
  hist[w][l] = 0;
  __syncthreads();
  #pragma unroll
  for (int r = 0; r < 4; ++r)
    atomicAdd(&hist[w][tgt[w * 256 + r * 64 + l]], 1);
  __syncthreads();
  if (tid < NCLS) {
    int run = 0;
    for (int ww = 0; ww < 16; ++ww) run += hist[ww][tid];
    ccnt[tid] = run;
    cnt[tid] = 0;
    hist[0][tid] = run;   // column-local overwrite, safe
  }
  __syncthreads();
  if (tid == 0) {
    int run = 0;
    for (int c = 0; c < NCLS; ++c) { int v = hist[0][c]; cbase[c] = run; run += v; }
  }
}

// ---------------- prep2: permuted bf16 cast + exact norms + far/near init ----------
// Block = one source row. Slot assignment via one atomicAdd per block; ordering is
// nondeterministic but far/near are idempotent min/max over the same pair multiset,
// so the final output is deterministic.
__global__ __launch_bounds__(256) void prep2_kernel(const float* __restrict__ X,
                                                    const int* __restrict__ tgt,
                                                    const int* __restrict__ cbase,
                                                    int* __restrict__ cnt,
                                                    unsigned short* __restrict__ Xp,
                                                    float* __restrict__ sq,
                                                    unsigned* __restrict__ far_bits,
                                                    unsigned* __restrict__ near_bits) {
  const int row = blockIdx.x;
  const int t = threadIdx.x;
  __shared__ int pos_s;
  if (t == 0) {
    const int c = tgt[row];
    pos_s = cbase[c] + atomicAdd(&cnt[c], 1);
  }
  __syncthreads();
  const int pos = pos_s;

  const float4* xr = (const float4*)(X + (size_t)row * DIM);
  float4 v0 = xr[t * 2 + 0];
  float4 v1 = xr[t * 2 + 1];
  float s = v0.x * v0.x + v0.y * v0.y + v0.z * v0.z + v0.w * v0.w
          + v1.x * v1.x + v1.y * v1.y + v1.z * v1.z + v1.w * v1.w;
  u16x8 o;
  o[0] = f32_to_bf16_rne(v0.x); o[1] = f32_to_bf16_rne(v0.y);
  o[2] = f32_to_bf16_rne(v0.z); o[3] = f32_to_bf16_rne(v0.w);
  o[4] = f32_to_bf16_rne(v1.x); o[5] = f32_to_bf16_rne(v1.y);
  o[6] = f32_to_bf16_rne(v1.z); o[7] = f32_to_bf16_rne(v1.w);
  *(u16x8*)(Xp + (size_t)pos * DIM + t * 8) = o;

  #pragma unroll
  for (int off = 32; off > 0; off >>= 1) s += __shfl_down(s, off, 64);
  __shared__ float wsum[4];
  const int lane = t & 63, w = t >> 6;
  if (lane == 0) wsum[w] = s;
  __syncthreads();
  if (t == 0) {
    sq[pos] = wsum[0] + wsum[1] + wsum[2] + wsum[3];
    far_bits[pos]  = 0u;           // 0.0f
    near_bits[pos] = 0x7f800000u;  // +inf
  }
}

// ---------------- per-class 64x64-unit GEMM with LDS staging ----------------
// grid = NCLS*16 (class c = bid>>4, unit slot q = bid&15). 256 thr = 4 waves.
// Class rows are CONTIGUOUS in Xp -> global_load_lds staging is line-clean.
// LDS tile = 64 rows x 64 cols bf16, 8 subtiles of 16x32 (1 KiB), st_16x32 XOR
// swizzle (R3-verified: 0 bank conflicts) via pre-swizzled source + swizzled read.
// Double-buffered, BK=64, 33 KiB LDS -> 4 blocks/CU.
__global__ __launch_bounds__(256) void cls_pairdist_kernel(
    const unsigned short* __restrict__ Xp, const float* __restrict__ sq,
    const int* __restrict__ cbase, const int* __restrict__ ccnt,
    unsigned* __restrict__ far_bits, unsigned* __restrict__ near_bits) {
  const int c = blockIdx.x >> 4, q = blockIdx.x & 15;
  const int n = ccnt[c];
  if (n <= 0) return;
  int T = (n + 63) >> 6; if (T > 8) T = 8;
  if (q >= T * T) return;
  const int base = cbase[c];

  __shared__ __align__(16) char Ab[2][8192];
  __shared__ __align__(16) char Bb[2][8192];
  __shared__ float sqr_s[64], sqc_s[64];

  const int tid  = threadIdx.x;
  const int lane = tid & 63, w = tid >> 6;   // wave 0..3
  const int wr = w >> 1, wc = w & 1;
  const int fr = lane & 15, hi4 = lane >> 4;
  const int srow = lane >> 2;                         // staging row within 16
  const int scol = ((lane & 3) * 8) ^ ((lane & 32) ? 16 : 0);  // pre-swizzled col
  const int ard  = fr * 64 + ((hi4 * 16) ^ ((lane & 8) << 2)); // swizzled read byte
  const float INF = __builtin_inff();

  for (int s = q; s < T * T; s += 16) {
    const int rt = s / T, ct = s - rt * T;
    const int arow = base + imin(rt * 64 + w * 16 + srow, n - 1);
    const int brow = base + imin(ct * 64 + w * 16 + srow, n - 1);
    const unsigned short* aglb = Xp + (size_t)arow * DIM + scol;
    const unsigned short* bglb = Xp + (size_t)brow * DIM + scol;

    if (tid < 64)       sqr_s[tid]      = sq[base + imin(rt * 64 + tid, n - 1)];
    else if (tid < 128) sqc_s[tid - 64] = sq[base + imin(ct * 64 + (tid - 64), n - 1)];

    // wave w stages subtiles (mc=w, kc=0/1) for A and B: dest uniform, HW lane*16
#define STG(buf, k0) do { \
    load_lds16(aglb + (k0),      &Ab[buf][w * 2048]); \
    load_lds16(aglb + (k0) + 32, &Ab[buf][w * 2048 + 1024]); \
    load_lds16(bglb + (k0),      &Bb[buf][w * 2048]); \
    load_lds16(bglb + (k0) + 32, &Bb[buf][w * 2048 + 1024]); } while (0)

    STG(0, 0);
    __syncthreads();   // drains vmcnt(0) lgkmcnt(0)

    f32x4 acc[2][2] = {};
    for (int kt = 0; kt < NTK; ++kt) {
      const int cur = kt & 1;
      if (kt + 1 < NTK) STG(cur ^ 1, (kt + 1) * 64);
      bf16x8 a[2][2], b[2][2];
      #pragma unroll
      for (int mp = 0; mp < 2; ++mp)
        #pragma unroll
        for (int kh = 0; kh < 2; ++kh) {
          a[mp][kh] = *(const bf16x8*)(&Ab[cur][((wr * 2 + mp) * 2 + kh) * 1024 + ard]);
          b[mp][kh] = *(const bf16x8*)(&Bb[cur][((wc * 2 + mp) * 2 + kh) * 1024 + ard]);
        }
      #pragma unroll
      for (int mp = 0; mp < 2; ++mp)
        #pragma unroll
        for (int np = 0; np < 2; ++np)
          #pragma unroll
          for (int kh = 0; kh < 2; ++kh)
            acc[mp][np] = __builtin_amdgcn_mfma_f32_16x16x32_bf16(
                a[mp][kh], b[np][kh], acc[mp][np], 0, 0, 0);
      __syncthreads();   // buf[cur] reads done before next iter re-stages it
    }
#undef STG

    // epilogue: d^2 on rows owned by this wave (row-side only; all ordered units exist)
    #pragma unroll
    for (int mp = 0; mp < 2; ++mp) {
      #pragma unroll
      for (int r = 0; r < 4; ++r) {
        const int lrow = wr * 32 + mp * 16 + hi4 * 4 + r;     // 0..63 in unit
        const int ui = base + imin(rt * 64 + lrow, n - 1);
        const float sqr = sqr_s[lrow];
        float fmx = 0.0f, nmn = INF;
        #pragma unroll
        for (int np = 0; np < 2; ++np) {
          const int lcol = wc * 32 + np * 16 + fr;
          const int uj = base + imin(ct * 64 + lcol, n - 1);
          const float d2 = fmaf(-2.0f, acc[mp][np][r], sqr + sqc_s[lcol]);
          fmx = fmaxf(fmx, d2);
          if (ui != uj) nmn = fminf(nmn, d2);
        }
        #pragma unroll
        for (int sh = 1; sh < 16; sh <<= 1) {
          fmx = fmaxf(fmx, __shfl_xor(fmx, sh, 64));
          nmn = fminf(nmn, __shfl_xor(nmn, sh, 64));
        }
        if (fr == 0) {
          atomicMax(&far_bits[ui],  __float_as_uint(sqrtf(fmaxf(fmx, 1e-12f))));
          atomicMin(&near_bits[ui], __float_as_uint(sqrtf(fmaxf(nmn, 1e-12f))));
        }
      }
    }
    __syncthreads();   // protect sqr_s/sqc_s/Ab[0] before next s-iter
  }
}

// ---------------- final deterministic reduction (permuted space == same mean) ------
__global__ __launch_bounds__(256) void finalize_kernel(
    const unsigned* __restrict__ far_bits, const unsigned* __restrict__ near_bits,
    float* __restrict__ out) {
  __shared__ float red[256];
  const int t = threadIdx.x;
  float s = 0.0f;
  for (int i = t; i < N_PTS; i += 256) {
    float fa = __uint_as_float(far_bits[i]);
    float ne = __uint_as_float(near_bits[i]);
    s += fmaxf(fa - ne, 0.0f);   // near=+inf -> -inf -> 0
  }
  red[t] = s;
  __syncthreads();
  for (int off = 128; off > 0; off >>= 1) {
    if (t < off) red[t] += red[t + off];
    __syncthreads();
  }
  if (t == 0) out[0] = red[0] / (float)N_PTS;
}

extern "C" void kernel_launch(void* const* d_in, const int* in_sizes, int n_in,
                              void* d_out, int out_size, void* d_ws, size_t ws_size,
                              hipStream_t stream) {
  const float* X   = (const float*)d_in[0];
  const int*   tgt = (const int*)d_in[1];
  float*       out = (float*)d_out;

  char* ws = (char*)d_ws;
  const size_t XB_BYTES = (size_t)N_PTS * DIM * 2;   // 16 MiB
  unsigned short* Xp = (unsigned short*)ws;
  float*    sq     = (float*)(ws + XB_BYTES);
  unsigned* far_b  = (unsigned*)(ws + XB_BYTES + N_PTS * 4);
  unsigned* near_b = (unsigned*)(ws + XB_BYTES + N_PTS * 8);
  int*      cbs    = (int*)(ws + XB_BYTES + N_PTS * 12);
  int*      ccn    = (int*)(ws + XB_BYTES + N_PTS * 12 + 256);
  int*      cnt    = (int*)(ws + XB_BYTES + N_PTS * 12 + 512);

  bucket_kernel<<<1, 1024, 0, stream>>>(tgt, cbs, ccn, cnt);
  prep2_kernel<<<N_PTS, 256, 0, stream>>>(X, tgt, cbs, cnt, Xp, sq, far_b, near_b);
  cls_pairdist_kernel<<<NCLS * 16, 256, 0, stream>>>(Xp, sq, cbs, ccn, far_b, near_b);
  finalize_kernel<<<1, 256, 0, stream>>>(far_b, near_b, out);
}

// Round 8
// 36.336 us; speedup vs baseline: 2.0508x; 2.0508x over previous
//
#include <hip/hip_runtime.h>
#include <hip/hip_bf16.h>
#include <cstdint>
#include <cstddef>

#define N_PTS 4096
#define DIM   2048
#define NCLS  64

typedef __bf16 bf16x8 __attribute__((ext_vector_type(8)));
typedef float  f32x4  __attribute__((ext_vector_type(4)));

__device__ __forceinline__ unsigned short f32_to_bf16_rne(float f) {
  unsigned u = __float_as_uint(f);
  u += 0x7fffu + ((u >> 16) & 1u);
  return (unsigned short)(u >> 16);
}
__device__ __forceinline__ int imin(int a, int b) { return a < b ? a : b; }

// ---------------- bucket: class histogram + prefix + scatter (R5-verified) ---------
__global__ __launch_bounds__(1024) void bucket_kernel(const int* __restrict__ tgt,
                                                      int* __restrict__ perm,
                                                      int* __restrict__ cbase,
                                                      int* __restrict__ ccnt) {
  __shared__ int hist[16][NCLS];
  __shared__ int woff[16][NCLS];
  __shared__ int cbs[NCLS];
  const int tid = threadIdx.x;
  const int w = tid >> 6, l = tid & 63;
  hist[w][l] = 0;
  __syncthreads();
  int cls[4];
  #pragma unroll
  for (int r = 0; r < 4; ++r) {
    cls[r] = tgt[w * 256 + r * 64 + l];
    atomicAdd(&hist[w][cls[r]], 1);
  }
  __syncthreads();
  if (tid < NCLS) {
    int run = 0;
    for (int ww = 0; ww < 16; ++ww) { woff[ww][tid] = run; run += hist[ww][tid]; }
    ccnt[tid] = run;
    cbs[tid] = run;
  }
  __syncthreads();
  if (tid == 0) {
    int run = 0;
    for (int c = 0; c < NCLS; ++c) { int t2 = cbs[c]; cbs[c] = run; run += t2; }
  }
  __syncthreads();
  if (tid < NCLS) {
    cbase[tid] = cbs[tid];
    for (int ww = 0; ww < 16; ++ww) woff[ww][tid] += cbs[tid];
  }
  __syncthreads();
  #pragma unroll
  for (int r = 0; r < 4; ++r) {
    int pos = atomicAdd(&woff[w][cls[r]], 1);
    perm[pos] = w * 256 + r * 64 + l;
  }
}

// ---------------- gram: per (class, K-quarter) partial 64x64 Gram ----------------
// grid = NCLS*4 (c = bid>>2, K-quarter slot = bid&3), 512 thr = 8 waves.
// Stage: 64 rows x 512 fp32 cols -> bf16 into swizzled LDS (16x32 subtiles,
// XOR-32-byte on row-bit3; R3-verified 0-conflict pattern), ONE barrier.
// Compute: 16 fragments (4m x 4n) over 8 waves, 16 kfrags each, from LDS.
// Store partial Gram row-major to Gpart[(c*16+u)*4+kq][64][64].
__global__ __launch_bounds__(512) void gram_kernel(
    const float* __restrict__ X, const int* __restrict__ perm,
    const int* __restrict__ cbase, const int* __restrict__ ccnt,
    float* __restrict__ Gpart) {
  const int c = blockIdx.x >> 2, slot = blockIdx.x & 3;
  const int n = ccnt[c];
  if (n <= 0) return;
  int T = (n + 63) >> 6; if (T > 4) T = 4;   // supports class size <= 256
  const int base = cbase[c];

  __shared__ __align__(16) char Asm[65536];
  __shared__ __align__(16) char Bsm[65536];

  const int tid = threadIdx.x;
  const int lane = tid & 63, w = tid >> 6;
  const int fr = lane & 15, hi4 = lane >> 4;
  const int srow = tid >> 3, sc8 = tid & 7;   // staging: 8 threads per row
  const int ard = (fr << 6) + ((hi4 << 4) ^ ((lane & 8) << 2));
  const int m = w >> 1, n0 = (w & 1) * 2;

  const int items = T * T * 4;
  for (int s = slot; s < items; s += 4) {
    const int kq = s & 3;
    const int u = s >> 2;
    const int rt = u / T, ct = u - rt * T;
    const bool dup = (rt == ct);

    // ---- stage A tile (rows of rt) ----
    {
      const int arow = perm[base + imin(rt * 64 + srow, n - 1)];
      const float4* ap = (const float4*)(X + (size_t)arow * DIM + kq * 512);
      float4 va[16];
      #pragma unroll
      for (int it = 0; it < 16; ++it) va[it] = ap[sc8 + it * 8];
      #pragma unroll
      for (int it = 0; it < 16; ++it) {
        const int col = (sc8 + it * 8) * 4;
        ushort4 o;
        o.x = f32_to_bf16_rne(va[it].x); o.y = f32_to_bf16_rne(va[it].y);
        o.z = f32_to_bf16_rne(va[it].z); o.w = f32_to_bf16_rne(va[it].w);
        const int byte = (((srow >> 4) * 16 + (col >> 5)) << 10) + ((srow & 15) << 6)
                       + (((col & 31) << 1) ^ ((srow & 8) << 2));
        *(ushort4*)(Asm + byte) = o;
      }
    }
    // ---- stage B tile (rows of ct) unless identical ----
    if (!dup) {
      const int brow = perm[base + imin(ct * 64 + srow, n - 1)];
      const float4* bp = (const float4*)(X + (size_t)brow * DIM + kq * 512);
      float4 vb[16];
      #pragma unroll
      for (int it = 0; it < 16; ++it) vb[it] = bp[sc8 + it * 8];
      #pragma unroll
      for (int it = 0; it < 16; ++it) {
        const int col = (sc8 + it * 8) * 4;
        ushort4 o;
        o.x = f32_to_bf16_rne(vb[it].x); o.y = f32_to_bf16_rne(vb[it].y);
        o.z = f32_to_bf16_rne(vb[it].z); o.w = f32_to_bf16_rne(vb[it].w);
        const int byte = (((srow >> 4) * 16 + (col >> 5)) << 10) + ((srow & 15) << 6)
                       + (((col & 31) << 1) ^ ((srow & 8) << 2));
        *(ushort4*)(Bsm + byte) = o;
      }
    }
    __syncthreads();

    const char* Bb = dup ? Asm : Bsm;
    f32x4 acc0 = {}, acc1 = {};
    #pragma unroll
    for (int kk = 0; kk < 16; ++kk) {
      bf16x8 a  = *(const bf16x8*)(Asm + ((m * 16 + kk) << 10) + ard);
      bf16x8 b0 = *(const bf16x8*)(Bb + (((n0    ) * 16 + kk) << 10) + ard);
      bf16x8 b1 = *(const bf16x8*)(Bb + (((n0 + 1) * 16 + kk) << 10) + ard);
      acc0 = __builtin_amdgcn_mfma_f32_16x16x32_bf16(a, b0, acc0, 0, 0, 0);
      acc1 = __builtin_amdgcn_mfma_f32_16x16x32_bf16(a, b1, acc1, 0, 0, 0);
    }

    float* gd = Gpart + (((size_t)(c * 16 + u) * 4 + kq) << 12);
    const int r0 = m * 16 + hi4 * 4;
    #pragma unroll
    for (int r = 0; r < 4; ++r) {
      gd[(r0 + r) * 64 + n0 * 16 + fr]       = acc0[r];
      gd[(r0 + r) * 64 + (n0 + 1) * 16 + fr] = acc1[r];
    }
    __syncthreads();   // protect LDS before next item restages
  }
}

// ---------------- combine: sum K-partials, d^2, far/near per row, loss[orig] ------
// 64 blocks (one class), 512 thr: 8 threads per row (8 cols each).
// loss indexed by ORIGINAL point id -> final sum is order-fixed & deterministic.
__global__ __launch_bounds__(512) void combine_kernel(
    const float* __restrict__ Gpart, const int* __restrict__ perm,
    const int* __restrict__ cbase, const int* __restrict__ ccnt,
    float* __restrict__ loss) {
  const int c = blockIdx.x;
  const int n = ccnt[c];
  if (n <= 0) return;
  int T = (n + 63) >> 6; if (T > 4) T = 4;
  const int base = cbase[c];
  const float* gc = Gpart + ((size_t)c << 18);   // c * 16*4*4096 floats

  __shared__ float diag[256];
  for (int j = threadIdx.x; j < T * 64; j += 512) {
    const int jt = j >> 6, jp = j & 63;
    const float* gu = gc + (((jt * T + jt) * 4) << 12) + jp * 65;
    diag[j] = ((gu[0] + gu[4096]) + gu[8192]) + gu[12288];
  }
  __syncthreads();

  const int tid = threadIdx.x;
  const int rsub = tid >> 3, cq = tid & 7;
  const float INF = __builtin_inff();
  for (int rt = 0; rt < T; ++rt) {
    const int row = rt * 64 + rsub;
    if (row >= n) continue;              // uniform within each 8-lane quad
    const float di = diag[row];
    float fmx = 0.0f, nmn = INF;
    for (int ct = 0; ct < T; ++ct) {
      const float* gu = gc + (((rt * T + ct) * 4) << 12) + rsub * 64 + cq * 8;
      f32x4 g0 = *(const f32x4*)(gu);
      f32x4 g1 = *(const f32x4*)(gu + 4);
      g0 += *(const f32x4*)(gu + 4096);  g1 += *(const f32x4*)(gu + 4100);
      g0 += *(const f32x4*)(gu + 8192);  g1 += *(const f32x4*)(gu + 8196);
      g0 += *(const f32x4*)(gu + 12288); g1 += *(const f32x4*)(gu + 12292);
      #pragma unroll
      for (int i = 0; i < 8; ++i) {
        const int col = ct * 64 + cq * 8 + i;
        const float gv = (i < 4) ? g0[i] : g1[i - 4];
        if (col < n) {
          const float d2 = fmaf(-2.0f, gv, di + diag[col]);
          fmx = fmaxf(fmx, d2);
          if (col != row) nmn = fminf(nmn, d2);
        }
      }
    }
    fmx = fmaxf(fmx, __shfl_xor(fmx, 1, 64)); nmn = fminf(nmn, __shfl_xor(nmn, 1, 64));
    fmx = fmaxf(fmx, __shfl_xor(fmx, 2, 64)); nmn = fminf(nmn, __shfl_xor(nmn, 2, 64));
    fmx = fmaxf(fmx, __shfl_xor(fmx, 4, 64)); nmn = fminf(nmn, __shfl_xor(nmn, 4, 64));
    if (cq == 0) {
      const float fa = sqrtf(fmaxf(fmx, 1e-12f));
      const float ne = sqrtf(fmaxf(nmn, 1e-12f));   // nmn=+inf (n==1) -> 0 loss
      loss[perm[base + row]] = fmaxf(fa - ne, 0.0f);
    }
  }
}

// ---------------- final: fixed-order deterministic mean ----------------
__global__ __launch_bounds__(256) void final_kernel(const float* __restrict__ loss,
                                                    float* __restrict__ out) {
  __shared__ float red[256];
  const int t = threadIdx.x;
  float s = 0.0f;
  for (int i = t; i < N_PTS / 4; i += 256) {
    f32x4 v = ((const f32x4*)loss)[i];
    s += ((v[0] + v[1]) + v[2]) + v[3];
  }
  red[t] = s;
  __syncthreads();
  for (int off = 128; off > 0; off >>= 1) {
    if (t < off) red[t] += red[t + off];
    __syncthreads();
  }
  if (t == 0) out[0] = red[0] / (float)N_PTS;
}

extern "C" void kernel_launch(void* const* d_in, const int* in_sizes, int n_in,
                              void* d_out, int out_size, void* d_ws, size_t ws_size,
                              hipStream_t stream) {
  const float* X   = (const float*)d_in[0];
  const int*   tgt = (const int*)d_in[1];
  float*       out = (float*)d_out;

  char* ws = (char*)d_ws;
  float* Gpart = (float*)ws;                                   // 64 MiB
  int*   perm  = (int*)(ws + (size_t)(64u << 20));             // 16 KiB
  int*   cbs   = (int*)(ws + (size_t)(64u << 20) + 16384);
  int*   ccn   = (int*)(ws + (size_t)(64u << 20) + 16384 + 256);
  float* loss  = (float*)(ws + (size_t)(64u << 20) + 16384 + 512);  // 16 KiB

  bucket_kernel<<<1, 1024, 0, stream>>>(tgt, perm, cbs, ccn);
  gram_kernel<<<NCLS * 4, 512, 0, stream>>>(X, perm, cbs, ccn, Gpart);
  combine_kernel<<<NCLS, 512, 0, stream>>>(Gpart, perm, cbs, ccn, loss);
  final_kernel<<<1, 256, 0, stream>>>(loss, out);
}

// Round 9
// 36.258 us; speedup vs baseline: 2.0552x; 1.0021x over previous
//
#include <hip/hip_runtime.h>
#include <hip/hip_bf16.h>
#include <cstdint>
#include <cstddef>

#define N_PTS 4096
#define DIM   2048
#define NCLS  64
#define NCH   8            // K-chunks of 256 floats
#define CHUNK 256
#define MAXT  4            // supports class size <= 256 (clamped)

typedef __bf16 bf16x8 __attribute__((ext_vector_type(8)));
typedef float  f32x4  __attribute__((ext_vector_type(4)));

__device__ __forceinline__ unsigned short f32_to_bf16_rne(float f) {
  unsigned u = __float_as_uint(f);
  u += 0x7fffu + ((u >> 16) & 1u);
  return (unsigned short)(u >> 16);
}
__device__ __forceinline__ int imin(int a, int b) { return a < b ? a : b; }

// ---------------- bucket: class histogram + prefix + scatter (R5-verified) ---------
__global__ __launch_bounds__(1024) void bucket_kernel(const int* __restrict__ tgt,
                                                      int* __restrict__ perm,
                                                      int* __restrict__ cbase,
                                                      int* __restrict__ ccnt) {
  __shared__ int hist[16][NCLS];
  __shared__ int woff[16][NCLS];
  __shared__ int cbs[NCLS];
  const int tid = threadIdx.x;
  const int w = tid >> 6, l = tid & 63;
  hist[w][l] = 0;
  __syncthreads();
  int cls[4];
  #pragma unroll
  for (int r = 0; r < 4; ++r) {
    cls[r] = tgt[w * 256 + r * 64 + l];
    atomicAdd(&hist[w][cls[r]], 1);
  }
  __syncthreads();
  if (tid < NCLS) {
    int run = 0;
    for (int ww = 0; ww < 16; ++ww) { woff[ww][tid] = run; run += hist[ww][tid]; }
    ccnt[tid] = run;
    cbs[tid] = run;
  }
  __syncthreads();
  if (tid == 0) {
    int run = 0;
    for (int c = 0; c < NCLS; ++c) { int t2 = cbs[c]; cbs[c] = run; run += t2; }
  }
  __syncthreads();
  if (tid < NCLS) {
    cbase[tid] = cbs[tid];
    for (int ww = 0; ww < 16; ++ww) woff[ww][tid] += cbs[tid];
  }
  __syncthreads();
  #pragma unroll
  for (int r = 0; r < 4; ++r) {
    int pos = atomicAdd(&woff[w][cls[r]], 1);
    perm[pos] = w * 256 + r * 64 + l;
  }
}

// ---------------- gram: per (class, K-chunk) ALL-tile partial Grams ----------------
// grid = NCLS*NCH (c = bid>>3, kc = bid&7), 512 thr = 8 waves.
// Stage class's T*64 rows x 256-col chunk fp32->bf16 into swizzled LDS ONCE
// (<=128 KiB), one barrier, then all T*T 64x64 tiles from LDS (no more barriers).
// Swizzle/read pattern identical to R8 (end-to-end verified, 0 bank conflicts).
// Gpart[c][u=rt*4+ct][kc][64][64] row-major partial Gram.
__global__ __launch_bounds__(512) void gram_kernel(
    const float* __restrict__ X, const int* __restrict__ perm,
    const int* __restrict__ cbase, const int* __restrict__ ccnt,
    float* __restrict__ Gpart) {
  const int c = blockIdx.x >> 3, kc = blockIdx.x & 7;
  const int n = ccnt[c];
  if (n <= 0) return;
  int T = (n + 63) >> 6; if (T > MAXT) T = MAXT;
  const int base = cbase[c];

  __shared__ __align__(16) char sm[131072];   // T*64 rows x 256 cols bf16, swizzled

  const int tid = threadIdx.x;
  const int lane = tid & 63, w = tid >> 6;
  const int fr = lane & 15, hi4 = lane >> 4;
  const int srow8 = tid >> 3, sc = tid & 7;    // staging: 8 threads per row

  // ---- stage (one pass per 64-row group) ----
  for (int p = 0; p < T; ++p) {
    const int r = p * 64 + srow8;
    const int grow = perm[base + imin(r, n - 1)];
    const float4* src = (const float4*)(X + (size_t)grow * DIM + kc * CHUNK);
    float4 v[8];
    #pragma unroll
    for (int it = 0; it < 8; ++it) v[it] = src[sc + it * 8];
    #pragma unroll
    for (int it = 0; it < 8; ++it) {
      const int col = (sc + it * 8) * 4;
      ushort4 o;
      o.x = f32_to_bf16_rne(v[it].x); o.y = f32_to_bf16_rne(v[it].y);
      o.z = f32_to_bf16_rne(v[it].z); o.w = f32_to_bf16_rne(v[it].w);
      const int byte = (((r >> 4) * 8 + (col >> 5)) << 10) + ((r & 15) << 6)
                     + (((col & 31) << 1) ^ ((r & 8) << 2));
      *(ushort4*)(sm + byte) = o;
    }
  }
  __syncthreads();

  // ---- compute all T*T tiles; wave owns frag-units (m, nn0) and (m, nn0+1) ----
  const int ard = (fr << 6) + ((hi4 << 4) ^ ((lane & 8) << 2));
  const int m = w >> 1, nn0 = (w & 1) * 2;

  for (int rt = 0; rt < T; ++rt) {
    for (int ct = 0; ct < T; ++ct) {
      f32x4 acc0 = {}, acc1 = {};
      #pragma unroll
      for (int kk = 0; kk < 8; ++kk) {
        bf16x8 a  = *(const bf16x8*)(sm + ((((rt * 4 + m) * 8) + kk) << 10) + ard);
        bf16x8 b0 = *(const bf16x8*)(sm + ((((ct * 4 + nn0) * 8) + kk) << 10) + ard);
        bf16x8 b1 = *(const bf16x8*)(sm + ((((ct * 4 + nn0 + 1) * 8) + kk) << 10) + ard);
        acc0 = __builtin_amdgcn_mfma_f32_16x16x32_bf16(a, b0, acc0, 0, 0, 0);
        acc1 = __builtin_amdgcn_mfma_f32_16x16x32_bf16(a, b1, acc1, 0, 0, 0);
      }
      float* gd = Gpart + ((((size_t)c * 16 + (rt * 4 + ct)) * NCH + kc) << 12);
      const int r0 = m * 16 + hi4 * 4;
      #pragma unroll
      for (int r = 0; r < 4; ++r) {
        gd[(r0 + r) * 64 + nn0 * 16 + fr]       = acc0[r];
        gd[(r0 + r) * 64 + (nn0 + 1) * 16 + fr] = acc1[r];
      }
    }
  }
}

// ---------------- combine: fixed-order chunk sum, d^2, far/near, loss[orig] --------
// 64 blocks (one class), 512 thr = 8 threads per row x 64 rows per pass.
// Diagonal of the summed Gram = ||x_bf16||^2 exactly -> d^2(i,i) = 0 exactly.
__global__ __launch_bounds__(512) void combine_kernel(
    const float* __restrict__ Gpart, const int* __restrict__ perm,
    const int* __restrict__ cbase, const int* __restrict__ ccnt,
    float* __restrict__ loss) {
  const int c = blockIdx.x;
  const int n = ccnt[c];
  if (n <= 0) return;
  int T = (n + 63) >> 6; if (T > MAXT) T = MAXT;
  const int base = cbase[c];
  const float* gc = Gpart + ((size_t)c * 16 * NCH << 12);

  __shared__ float diag[MAXT * 64];
  for (int j = threadIdx.x; j < T * 64; j += 512) {
    const int jt = j >> 6, jp = j & 63;
    const float* gu = gc + (((size_t)(jt * 5) * NCH) << 12) + jp * 65;
    float s = 0.0f;
    #pragma unroll
    for (int k = 0; k < NCH; ++k) s += gu[k << 12];
    diag[j] = s;
  }
  __syncthreads();

  const int tid = threadIdx.x;
  const int rsub = tid >> 3, cq = tid & 7;
  const float INF = __builtin_inff();
  for (int rt = 0; rt < T; ++rt) {
    const int row = rt * 64 + rsub;
    if (row >= n) continue;                  // uniform within each 8-lane group
    const float di = diag[row];
    float fmx = 0.0f, nmn = INF;
    for (int ct = 0; ct < T; ++ct) {
      const float* gu = gc + (((size_t)(rt * 4 + ct) * NCH) << 12) + rsub * 64 + cq * 8;
      f32x4 g0 = {}, g1 = {};
      #pragma unroll
      for (int k = 0; k < NCH; ++k) {
        g0 += *(const f32x4*)(gu + (k << 12));
        g1 += *(const f32x4*)(gu + (k << 12) + 4);
      }
      #pragma unroll
      for (int i = 0; i < 8; ++i) {
        const int col = ct * 64 + cq * 8 + i;
        const float gv = (i < 4) ? g0[i] : g1[i - 4];
        if (col < n) {
          const float d2 = fmaf(-2.0f, gv, di + diag[col]);
          fmx = fmaxf(fmx, d2);
          if (col != row) nmn = fminf(nmn, d2);
        }
      }
    }
    fmx = fmaxf(fmx, __shfl_xor(fmx, 1, 64)); nmn = fminf(nmn, __shfl_xor(nmn, 1, 64));
    fmx = fmaxf(fmx, __shfl_xor(fmx, 2, 64)); nmn = fminf(nmn, __shfl_xor(nmn, 2, 64));
    fmx = fmaxf(fmx, __shfl_xor(fmx, 4, 64)); nmn = fminf(nmn, __shfl_xor(nmn, 4, 64));
    if (cq == 0) {
      const float fa = sqrtf(fmaxf(fmx, 1e-12f));
      const float ne = sqrtf(fmaxf(nmn, 1e-12f));  // nmn=+inf (n==1) -> loss 0
      loss[perm[base + row]] = fmaxf(fa - ne, 0.0f);
    }
  }
}

// ---------------- final: fixed-order deterministic mean ----------------
__global__ __launch_bounds__(256) void final_kernel(const float* __restrict__ loss,
                                                    float* __restrict__ out) {
  __shared__ float red[256];
  const int t = threadIdx.x;
  float s = 0.0f;
  for (int i = t; i < N_PTS / 4; i += 256) {
    f32x4 v = ((const f32x4*)loss)[i];
    s += ((v[0] + v[1]) + v[2]) + v[3];
  }
  red[t] = s;
  __syncthreads();
  for (int off = 128; off > 0; off >>= 1) {
    if (t < off) red[t] += red[t + off];
    __syncthreads();
  }
  if (t == 0) out[0] = red[0] / (float)N_PTS;
}

extern "C" void kernel_launch(void* const* d_in, const int* in_sizes, int n_in,
                              void* d_out, int out_size, void* d_ws, size_t ws_size,
                              hipStream_t stream) {
  const float* X   = (const float*)d_in[0];
  const int*   tgt = (const int*)d_in[1];
  float*       out = (float*)d_out;

  char* ws = (char*)d_ws;
  float* Gpart = (float*)ws;                                    // 128 MiB
  char*  tail  = ws + ((size_t)128u << 20);
  int*   perm  = (int*)tail;                                    // 16 KiB
  int*   cbs   = (int*)(tail + 16384);
  int*   ccn   = (int*)(tail + 16384 + 256);
  float* loss  = (float*)(tail + 16384 + 512);                  // 16 KiB

  bucket_kernel<<<1, 1024, 0, stream>>>(tgt, perm, cbs, ccn);
  gram_kernel<<<NCLS * NCH, 512, 0, stream>>>(X, perm, cbs, ccn, Gpart);
  combine_kernel<<<NCLS, 512, 0, stream>>>(Gpart, perm, cbs, ccn, loss);
  final_kernel<<<1, 256, 0, stream>>>(loss, out);
}